// Round 2
// baseline (449.560 us; speedup 1.0000x reference)
//
#include <hip/hip_runtime.h>

// Input:  x[b][c][h][w], B=8, C=32, H=512, W=512 (fp32)
// Output: out[b][q][c][h2][w2], q in {LL,LH,HL,HH}, h2=H/2=256, w2=W/2=256 (fp32)
//
// Each thread handles 4 output columns (8 input columns) of one output row:
//   loads  : 4x global_load_dwordx4 (two per input row)
//   stores : 4x global_store_dwordx4 (one 16B store per quadrant, nontemporal)
// Grid-stride with 2048 blocks (8 blocks/CU); 4,194,304 logical tiles / 524,288
// threads = exactly 8 iterations per thread, no tail.

#define B_   8
#define C_   32
#define H2_  256
#define W2_  256
#define WQ_  (W2_/4)            // 64 float4-wide output groups per row

typedef float v4f __attribute__((ext_vector_type(4)));

__global__ __launch_bounds__(256)
void WaveletTransform_14319420965150_kernel(const float* __restrict__ x,
                                            float* __restrict__ out) {
    const int total  = B_ * C_ * H2_ * WQ_;       // 4,194,304
    const int stride = gridDim.x * blockDim.x;    // 524,288

    const v4f* __restrict__ xin = (const v4f*)x;
    v4f* __restrict__ o         = (v4f*)out;
    const size_t qstride = (size_t)C_ * (H2_ * W2_ / 4);  // 524,288 v4f per quadrant

    for (int tid = blockIdx.x * blockDim.x + threadIdx.x; tid < total; tid += stride) {
        const int wq = tid & (WQ_ - 1);           // 0..63
        const int h2 = (tid >> 6) & (H2_ - 1);    // 0..255
        const int bc = tid >> 14;                 // b*32 + c, 0..255

        // input rows 2*h2 and 2*h2+1 of image bc; row = 512 floats = 128 v4f
        const size_t r0 = ((size_t)bc * 512 + 2 * h2) * (512 / 4) + 2 * wq;
        v4f t0 = xin[r0];        // cols 8wq+0..3 of top row
        v4f t1 = xin[r0 + 1];    // cols 8wq+4..7 of top row
        v4f u0 = xin[r0 + 128];  // cols 8wq+0..3 of bottom row
        v4f u1 = xin[r0 + 129];  // cols 8wq+4..7 of bottom row

        v4f LL, LH, HL, HH;
        { float s0 = t0.x + t0.y, d0 = t0.x - t0.y;
          float s1 = u0.x + u0.y, d1 = u0.x - u0.y;
          LL.x = (s0 + s1) * 0.5f; LH.x = (s0 - s1) * 0.5f;
          HL.x = (d0 + d1) * 0.5f; HH.x = (d0 - d1) * 0.5f; }
        { float s0 = t0.z + t0.w, d0 = t0.z - t0.w;
          float s1 = u0.z + u0.w, d1 = u0.z - u0.w;
          LL.y = (s0 + s1) * 0.5f; LH.y = (s0 - s1) * 0.5f;
          HL.y = (d0 + d1) * 0.5f; HH.y = (d0 - d1) * 0.5f; }
        { float s0 = t1.x + t1.y, d0 = t1.x - t1.y;
          float s1 = u1.x + u1.y, d1 = u1.x - u1.y;
          LL.z = (s0 + s1) * 0.5f; LH.z = (s0 - s1) * 0.5f;
          HL.z = (d0 + d1) * 0.5f; HH.z = (d0 - d1) * 0.5f; }
        { float s0 = t1.z + t1.w, d0 = t1.z - t1.w;
          float s1 = u1.z + u1.w, d1 = u1.z - u1.w;
          LL.w = (s0 + s1) * 0.5f; LH.w = (s0 - s1) * 0.5f;
          HL.w = (d0 + d1) * 0.5f; HH.w = (d0 - d1) * 0.5f; }

        // out v4f index: ((b*4 + q)*C + c)*H2*W2/4 + h2*W2/4 + wq
        const size_t ob = ((size_t)(bc >> 5) * (4 * C_) + (bc & (C_ - 1))) * (H2_ * W2_ / 4)
                        + (size_t)h2 * (W2_ / 4) + wq;
        __builtin_nontemporal_store(LL, &o[ob]);
        __builtin_nontemporal_store(LH, &o[ob +     qstride]);
        __builtin_nontemporal_store(HL, &o[ob + 2 * qstride]);
        __builtin_nontemporal_store(HH, &o[ob + 3 * qstride]);
    }
}

extern "C" void kernel_launch(void* const* d_in, const int* in_sizes, int n_in,
                              void* d_out, int out_size, void* d_ws, size_t ws_size,
                              hipStream_t stream) {
    const float* x = (const float*)d_in[0];
    float* out = (float*)d_out;
    const int block = 256;
    const int grid  = 2048;   // 8 blocks/CU x 256 CUs; 8 tiles per thread
    WaveletTransform_14319420965150_kernel<<<grid, block, 0, stream>>>(x, out);
}

// Round 3
// 434.902 us; speedup vs baseline: 1.0337x; 1.0337x over previous
//
#include <hip/hip_runtime.h>

// Input:  x[b][c][h][w], B=8, C=32, H=512, W=512 (fp32)
// Output: out[b][q][c][h2][w2], q in {LL,LH,HL,HH}, h2=H/2=256, w2=W/2=256 (fp32)
//
// Each thread handles 4 output columns (8 input columns) of one output row:
//   loads  : 4x global_load_dwordx4 (two per input row)
//   stores : 4x global_store_dwordx4 (one 16B store per quadrant, PLAIN —
//            nt stores measured 165us @ 2.4TB/s; letting L2/L3 absorb the
//            write stream decouples it from the read stream at HBM)
// Grid-stride with 2048 blocks (8 blocks/CU); 4,194,304 logical tiles / 524,288
// threads = exactly 8 iterations per thread, no tail.

#define B_   8
#define C_   32
#define H2_  256
#define W2_  256
#define WQ_  (W2_/4)            // 64 float4-wide output groups per row

typedef float v4f __attribute__((ext_vector_type(4)));

__global__ __launch_bounds__(256)
void WaveletTransform_14319420965150_kernel(const float* __restrict__ x,
                                            float* __restrict__ out) {
    const int total  = B_ * C_ * H2_ * WQ_;       // 4,194,304
    const int stride = gridDim.x * blockDim.x;    // 524,288

    const v4f* __restrict__ xin = (const v4f*)x;
    v4f* __restrict__ o         = (v4f*)out;
    const size_t qstride = (size_t)C_ * (H2_ * W2_ / 4);  // 524,288 v4f per quadrant

    for (int tid = blockIdx.x * blockDim.x + threadIdx.x; tid < total; tid += stride) {
        const int wq = tid & (WQ_ - 1);           // 0..63
        const int h2 = (tid >> 6) & (H2_ - 1);    // 0..255
        const int bc = tid >> 14;                 // b*32 + c, 0..255

        // input rows 2*h2 and 2*h2+1 of image bc; row = 512 floats = 128 v4f
        const size_t r0 = ((size_t)bc * 512 + 2 * h2) * (512 / 4) + 2 * wq;
        v4f t0 = xin[r0];        // cols 8wq+0..3 of top row
        v4f t1 = xin[r0 + 1];    // cols 8wq+4..7 of top row
        v4f u0 = xin[r0 + 128];  // cols 8wq+0..3 of bottom row
        v4f u1 = xin[r0 + 129];  // cols 8wq+4..7 of bottom row

        v4f LL, LH, HL, HH;
        { float s0 = t0.x + t0.y, d0 = t0.x - t0.y;
          float s1 = u0.x + u0.y, d1 = u0.x - u0.y;
          LL.x = (s0 + s1) * 0.5f; LH.x = (s0 - s1) * 0.5f;
          HL.x = (d0 + d1) * 0.5f; HH.x = (d0 - d1) * 0.5f; }
        { float s0 = t0.z + t0.w, d0 = t0.z - t0.w;
          float s1 = u0.z + u0.w, d1 = u0.z - u0.w;
          LL.y = (s0 + s1) * 0.5f; LH.y = (s0 - s1) * 0.5f;
          HL.y = (d0 + d1) * 0.5f; HH.y = (d0 - d1) * 0.5f; }
        { float s0 = t1.x + t1.y, d0 = t1.x - t1.y;
          float s1 = u1.x + u1.y, d1 = u1.x - u1.y;
          LL.z = (s0 + s1) * 0.5f; LH.z = (s0 - s1) * 0.5f;
          HL.z = (d0 + d1) * 0.5f; HH.z = (d0 - d1) * 0.5f; }
        { float s0 = t1.z + t1.w, d0 = t1.z - t1.w;
          float s1 = u1.z + u1.w, d1 = u1.z - u1.w;
          LL.w = (s0 + s1) * 0.5f; LH.w = (s0 - s1) * 0.5f;
          HL.w = (d0 + d1) * 0.5f; HH.w = (d0 - d1) * 0.5f; }

        // out v4f index: ((b*4 + q)*C + c)*H2*W2/4 + h2*W2/4 + wq
        const size_t ob = ((size_t)(bc >> 5) * (4 * C_) + (bc & (C_ - 1))) * (H2_ * W2_ / 4)
                        + (size_t)h2 * (W2_ / 4) + wq;
        o[ob]               = LL;
        o[ob +     qstride] = LH;
        o[ob + 2 * qstride] = HL;
        o[ob + 3 * qstride] = HH;
    }
}

extern "C" void kernel_launch(void* const* d_in, const int* in_sizes, int n_in,
                              void* d_out, int out_size, void* d_ws, size_t ws_size,
                              hipStream_t stream) {
    const float* x = (const float*)d_in[0];
    float* out = (float*)d_out;
    const int block = 256;
    const int grid  = 2048;   // 8 blocks/CU x 256 CUs; 8 tiles per thread
    WaveletTransform_14319420965150_kernel<<<grid, block, 0, stream>>>(x, out);
}